// Round 12
// baseline (197.723 us; speedup 1.0000x reference)
//
#include <hip/hip_runtime.h>

// Gated delta rule recurrence S_t = S_{t-1} @ A_t + B_t, outputs all S_t.
// T=128, B*H=64 chains, D=64. Chunked scan with NC=32 chunks of CH=4.
//   K1 (fold4): chunk summaries (PA,PB)     [2048 blocks, 3 barrier-free steps]
//   K2 (seq):   scan 32 summaries -> chunk-end states into out   [64 blocks]
//   K3 (scan4): in-chunk recurrence (3 steps) -> remaining states [2048 blocks]
// Split-bf16 MFMA (hi/lo, 3 products), transposed recurrence S^T <- A^T S^T.
// r12 STRUCTURE: each block pre-stages its ENTIRE chunk up front:
//   - 3 A tiles DMA'd HBM->LDS via width-4 global_load_lds into PITCH-65 rows
//     (bank=(k+m)%32: the stride-64 column reads become <=2-way = free).
//   - 3 B tiles in 3 named register sets (issue-order pinned by sched_barrier).
//   - ONE vmcnt(12)+barrier after staging (leaves B in flight); the 3 compute
//     steps then run with ZERO barriers (LDS read-only; B gets compiler-counted
//     waits). ~64KB DMA in flight per block x3 blocks/CU = deep memory queue.

constexpr int kT = 128;
constexpr int kBH = 64;
constexpr int kD = 64;
constexpr int kTile = kD * kD;
constexpr int kNC = 32;
constexpr int kCH = 4;
constexpr int kP = 65;  // LDS pitch (floats) for staged A tiles

typedef __attribute__((ext_vector_type(8))) short short8;
typedef __attribute__((ext_vector_type(4))) float f32x4;
using u32 = unsigned int;

union U8 { u32 u[4]; short8 s; };

__device__ __forceinline__ f32x4 mfma16(short8 a, short8 b, f32x4 c) {
  return __builtin_amdgcn_mfma_f32_16x16x32_bf16(a, b, c, 0, 0, 0);
}

#define SB0() __builtin_amdgcn_sched_barrier(0)

// split 2 floats into packed hi/lo bf16 pairs (1 v_cvt_pk each + exact residual)
__device__ __forceinline__ void pk_split(float a, float b, u32& h, u32& l) {
  u32 hu;
  asm("v_cvt_pk_bf16_f32 %0, %1, %2" : "=v"(hu) : "v"(a), "v"(b));
  const float ra = a - __uint_as_float(hu << 16);
  const float rb = b - __uint_as_float(hu & 0xffff0000u);
  u32 lu;
  asm("v_cvt_pk_bf16_f32 %0, %1, %2" : "=v"(lu) : "v"(ra), "v"(rb));
  h = hu;
  l = lu;
}

// Build one K=32 B-operand fragment from two C/D tiles (X = tile 2ks, Y = 2ks+1).
__device__ __forceinline__ short8 gather_frag(u32 p01, u32 p23, u32 q01, u32 q23,
                                              int ad0, int ad1, bool lowh) {
  U8 r;
  int x, y;
  x = __builtin_amdgcn_ds_bpermute(ad0, (int)p01);
  y = __builtin_amdgcn_ds_bpermute(ad0, (int)q01);
  r.u[0] = (u32)(lowh ? x : y);
  x = __builtin_amdgcn_ds_bpermute(ad0, (int)p23);
  y = __builtin_amdgcn_ds_bpermute(ad0, (int)q23);
  r.u[1] = (u32)(lowh ? x : y);
  x = __builtin_amdgcn_ds_bpermute(ad1, (int)p01);
  y = __builtin_amdgcn_ds_bpermute(ad1, (int)q01);
  r.u[2] = (u32)(lowh ? x : y);
  x = __builtin_amdgcn_ds_bpermute(ad1, (int)p23);
  y = __builtin_amdgcn_ds_bpermute(ad1, (int)q23);
  r.u[3] = (u32)(lowh ? x : y);
  return r.s;
}

// Read A^T fragment from pitch-65 row-major fp32 A tile in LDS:
// A[k0+j][row] at LDS dword (k0+j)*65 + row. Banks (k+row)%32 -> <=2-way.
__device__ __forceinline__ void read_afragT65(const float* sAbuf, int row, int k0,
                                              short8& ah, short8& al) {
  const float* base = sAbuf + k0 * kP + row;
  float d0 = base[0 * kP], d1 = base[1 * kP], d2 = base[2 * kP], d3 = base[3 * kP];
  float d4 = base[4 * kP], d5 = base[5 * kP], d6 = base[6 * kP], d7 = base[7 * kP];
  U8 h, l;
  u32 hu, lu;
  pk_split(d0, d1, hu, lu); h.u[0] = hu; l.u[0] = lu;
  pk_split(d2, d3, hu, lu); h.u[1] = hu; l.u[1] = lu;
  pk_split(d4, d5, hu, lu); h.u[2] = hu; l.u[2] = lu;
  pk_split(d6, d7, hu, lu); h.u[3] = hu; l.u[3] = lu;
  ah = h.s; al = l.s;
}

// Stage one A tile into pitch-65 LDS: 16 width-4 DMAs per wave, one row each
// (src = 256B contiguous per inst, coalesced; dest row base uniform).
#define ISSUE_A65(PTRA, SBUF)                                                   \
  do {                                                                          \
    const float* gp_ = (PTRA);                                                  \
    float* sb_ = (SBUF);                                                        \
    _Pragma("unroll") for (int it_ = 0; it_ < 16; ++it_) {                      \
      const int row_ = w * 16 + it_;                                            \
      __builtin_amdgcn_global_load_lds(                                         \
          (const __attribute__((address_space(1))) u32*)(gp_ + row_ * 64 + lane), \
          (__attribute__((address_space(3))) u32*)(sb_ + row_ * kP),            \
          4, 0, 0);                                                             \
    }                                                                           \
  } while (0)

#define LOAD_B4_INTO(R0, R1, R2, R3, PTRB)                                     \
  do {                                                                         \
    const float* Bt_ = (PTRB);                                                 \
    R0 = *reinterpret_cast<const f32x4*>(Bt_ + rowbase + 0 * 16 + q * 4);      \
    R1 = *reinterpret_cast<const f32x4*>(Bt_ + rowbase + 1 * 16 + q * 4);      \
    R2 = *reinterpret_cast<const f32x4*>(Bt_ + rowbase + 2 * 16 + q * 4);      \
    R3 = *reinterpret_cast<const f32x4*>(Bt_ + rowbase + 3 * 16 + q * 4);      \
  } while (0)

// ---------------- K1: fold over 4 elements, no barriers between steps ----------------
// One step: (pa,pb) <- (A^T pa, A^T pb + B^T), A from pitch-65 LDS tile SA,
// B^T from register set C0..C3.
#define STEP_FOLD(SA, C0, C1, C2, C3)                                         \
  do {                                                                        \
    f32x4 npa[4], npb[4];                                                     \
    npb[0] = C0; npb[1] = C1; npb[2] = C2; npb[3] = C3;                       \
    _Pragma("unroll") for (int cm = 0; cm < 4; ++cm)                          \
        npa[cm] = (f32x4){0.f, 0.f, 0.f, 0.f};                                \
    const float* sCur_ = &(SA)[0];                                            \
    _Pragma("unroll") for (int ks = 0; ks < 2; ++ks) {                        \
      u32 pa01h, pa01l, pa23h, pa23l, qa01h, qa01l, qa23h, qa23l;             \
      u32 pb01h, pb01l, pb23h, pb23l, qb01h, qb01l, qb23h, qb23l;             \
      pk_split(apa[2 * ks][0], apa[2 * ks][1], pa01h, pa01l);                 \
      pk_split(apa[2 * ks][2], apa[2 * ks][3], pa23h, pa23l);                 \
      pk_split(apa[2 * ks + 1][0], apa[2 * ks + 1][1], qa01h, qa01l);         \
      pk_split(apa[2 * ks + 1][2], apa[2 * ks + 1][3], qa23h, qa23l);         \
      pk_split(apb[2 * ks][0], apb[2 * ks][1], pb01h, pb01l);                 \
      pk_split(apb[2 * ks][2], apb[2 * ks][3], pb23h, pb23l);                 \
      pk_split(apb[2 * ks + 1][0], apb[2 * ks + 1][1], qb01h, qb01l);         \
      pk_split(apb[2 * ks + 1][2], apb[2 * ks + 1][3], qb23h, qb23l);         \
      const short8 bah = gather_frag(pa01h, pa23h, qa01h, qa23h, ad0, ad1, lowh); \
      const short8 bal = gather_frag(pa01l, pa23l, qa01l, qa23l, ad0, ad1, lowh); \
      const short8 bbh = gather_frag(pb01h, pb23h, qb01h, qb23h, ad0, ad1, lowh); \
      const short8 bbl = gather_frag(pb01l, pb23l, qb01l, qb23l, ad0, ad1, lowh); \
      _Pragma("unroll") for (int cm = 0; cm < 4; ++cm) {                      \
        short8 ah, al;                                                        \
        read_afragT65(sCur_, cm * 16 + l15, ks * 32 + q * 8, ah, al);         \
        npa[cm] = mfma16(ah, bah, npa[cm]);                                   \
        npa[cm] = mfma16(ah, bal, npa[cm]);                                   \
        npa[cm] = mfma16(al, bah, npa[cm]);                                   \
        npb[cm] = mfma16(ah, bbh, npb[cm]);                                   \
        npb[cm] = mfma16(ah, bbl, npb[cm]);                                   \
        npb[cm] = mfma16(al, bbh, npb[cm]);                                   \
      }                                                                       \
    }                                                                         \
    _Pragma("unroll") for (int cm = 0; cm < 4; ++cm) {                        \
      apa[cm] = npa[cm];                                                      \
      apb[cm] = npb[cm];                                                      \
    }                                                                         \
  } while (0)

__global__ __attribute__((amdgpu_flat_work_group_size(256, 256),
                          amdgpu_waves_per_eu(3, 4)))
void gdr_fold4(const float* __restrict__ srcA, const float* __restrict__ srcB,
               float* __restrict__ dstA, float* __restrict__ dstB) {
  __shared__ float sA1[64 * kP], sA2[64 * kP], sA3[64 * kP];

  const int tid = threadIdx.x;
  const int lane = tid & 63, w = tid >> 6;
  const int q = lane >> 4, l15 = lane & 15;
  const int bh = blockIdx.x / kNC, ck = blockIdx.x % kNC;
  const long e0 = (long)bh + (long)ck * (kCH * kBH);  // tile idx of elem 0
  const int rowbase = (w * 16 + l15) * 64;
  const int ad0 = (l15 + ((lane >> 4) & 1) * 32) * 4;
  const int ad1 = ad0 + 64;
  const bool lowh = lane < 32;

  // acc init = element 0 (direct global read)
  f32x4 apa[4], apb[4];
  {
    const float* At = srcA + (size_t)e0 * kTile;
    const float* Bt = srcB + (size_t)e0 * kTile;
#pragma unroll
    for (int cm = 0; cm < 4; ++cm) {
      apa[cm] = *reinterpret_cast<const f32x4*>(At + rowbase + cm * 16 + q * 4);
      apb[cm] = *reinterpret_cast<const f32x4*>(Bt + rowbase + cm * 16 + q * 4);
    }
  }
  SB0();
  // stage A(1..3) -> LDS (48 DMA insts/wave, in flight together)
  ISSUE_A65(srcA + (size_t)(e0 + 1 * kBH) * kTile, sA1);
  ISSUE_A65(srcA + (size_t)(e0 + 2 * kBH) * kTile, sA2);
  ISSUE_A65(srcA + (size_t)(e0 + 3 * kBH) * kTile, sA3);
  SB0();
  // B(1..3) -> 3 named register sets (issue-order pinned)
  f32x4 r1a, r1b, r1c, r1d, r2a, r2b, r2c, r2d, r3a, r3b, r3c, r3d;
  LOAD_B4_INTO(r1a, r1b, r1c, r1d, srcB + (size_t)(e0 + 1 * kBH) * kTile);
  SB0();
  LOAD_B4_INTO(r2a, r2b, r2c, r2d, srcB + (size_t)(e0 + 2 * kBH) * kTile);
  SB0();
  LOAD_B4_INTO(r3a, r3b, r3c, r3d, srcB + (size_t)(e0 + 3 * kBH) * kTile);
  SB0();
  // ONE wait: drains acc + all A DMAs (oldest), leaves the 12 B loads in flight.
  asm volatile("s_waitcnt vmcnt(12)" ::: "memory");
  SB0();
  __builtin_amdgcn_s_barrier();
  SB0();

  // 3 barrier-free steps (compiler inserts counted vmcnt for each B set)
  STEP_FOLD(sA1, r1a, r1b, r1c, r1d);
  STEP_FOLD(sA2, r2a, r2b, r2c, r2d);
  STEP_FOLD(sA3, r3a, r3b, r3c, r3d);

  float* pao = dstA + (size_t)blockIdx.x * kTile;
  float* pbo = dstB + (size_t)blockIdx.x * kTile;
#pragma unroll
  for (int cm = 0; cm < 4; ++cm) {
    *reinterpret_cast<f32x4*>(pao + rowbase + cm * 16 + q * 4) = apa[cm];
    *reinterpret_cast<f32x4*>(pbo + rowbase + cm * 16 + q * 4) = apb[cm];
  }
}

// ---------------- K3: in-chunk recurrence, 3 barrier-free steps ----------------
#define STEP_SCAN(SA, C0, C1, C2, C3, TI)                                     \
  do {                                                                        \
    f32x4 nacc[4];                                                            \
    nacc[0] = C0; nacc[1] = C1; nacc[2] = C2; nacc[3] = C3;                   \
    const float* sCur_ = &(SA)[0];                                            \
    _Pragma("unroll") for (int ks = 0; ks < 2; ++ks) {                        \
      u32 p01h, p01l, p23h, p23l, q01h, q01l, q23h, q23l;                     \
      pk_split(acc[2 * ks][0], acc[2 * ks][1], p01h, p01l);                   \
      pk_split(acc[2 * ks][2], acc[2 * ks][3], p23h, p23l);                   \
      pk_split(acc[2 * ks + 1][0], acc[2 * ks + 1][1], q01h, q01l);           \
      pk_split(acc[2 * ks + 1][2], acc[2 * ks + 1][3], q23h, q23l);           \
      const short8 bfh = gather_frag(p01h, p23h, q01h, q23h, ad0, ad1, lowh); \
      const short8 bfl = gather_frag(p01l, p23l, q01l, q23l, ad0, ad1, lowh); \
      _Pragma("unroll") for (int cm = 0; cm < 4; ++cm) {                      \
        short8 ah, al;                                                        \
        read_afragT65(sCur_, cm * 16 + l15, ks * 32 + q * 8, ah, al);         \
        nacc[cm] = mfma16(ah, bfh, nacc[cm]);                                 \
        nacc[cm] = mfma16(ah, bfl, nacc[cm]);                                 \
        nacc[cm] = mfma16(al, bfh, nacc[cm]);                                 \
      }                                                                       \
    }                                                                         \
    const int t_ = tBase + (TI);                                              \
    float* o_ = out + ((size_t)t_ * kBH + bh) * kTile;                        \
    _Pragma("unroll") for (int cm = 0; cm < 4; ++cm) {                        \
      *reinterpret_cast<f32x4*>(o_ + rowbase + cm * 16 + q * 4) = nacc[cm];   \
      acc[cm] = nacc[cm];                                                     \
    }                                                                         \
  } while (0)

__global__ __attribute__((amdgpu_flat_work_group_size(256, 256),
                          amdgpu_waves_per_eu(3, 4)))
void gdr_scan4(const float* __restrict__ srcA, const float* __restrict__ srcB,
               const float* __restrict__ S0, float* __restrict__ out) {
  __shared__ float sA1[64 * kP], sA2[64 * kP], sA3[64 * kP];

  const int tid = threadIdx.x;
  const int lane = tid & 63, w = tid >> 6;
  const int q = lane >> 4, l15 = lane & 15;
  const int bh = blockIdx.x / kNC, ck = blockIdx.x % kNC;
  const long e0 = (long)bh + (long)ck * (kCH * kBH);
  const int tBase = ck * kCH;
  const int rowbase = (w * 16 + l15) * 64;
  const int ad0 = (l15 + ((lane >> 4) & 1) * 32) * 4;
  const int ad1 = ad0 + 64;
  const bool lowh = lane < 32;

  // acc init from chunk-start state (S0 or previous chunk-end written by K2)
  f32x4 acc[4];
  {
    const float* Sb = (tBase == 0) ? (S0 + (size_t)bh * kTile)
                                   : (out + ((size_t)(tBase - 1) * kBH + bh) * kTile);
#pragma unroll
    for (int cm = 0; cm < 4; ++cm)
      acc[cm] = *reinterpret_cast<const f32x4*>(Sb + rowbase + cm * 16 + q * 4);
  }
  SB0();
  ISSUE_A65(srcA + (size_t)e0 * kTile, sA1);
  ISSUE_A65(srcA + (size_t)(e0 + 1 * kBH) * kTile, sA2);
  ISSUE_A65(srcA + (size_t)(e0 + 2 * kBH) * kTile, sA3);
  SB0();
  f32x4 r1a, r1b, r1c, r1d, r2a, r2b, r2c, r2d, r3a, r3b, r3c, r3d;
  LOAD_B4_INTO(r1a, r1b, r1c, r1d, srcB + (size_t)e0 * kTile);
  SB0();
  LOAD_B4_INTO(r2a, r2b, r2c, r2d, srcB + (size_t)(e0 + 1 * kBH) * kTile);
  SB0();
  LOAD_B4_INTO(r3a, r3b, r3c, r3d, srcB + (size_t)(e0 + 2 * kBH) * kTile);
  SB0();
  asm volatile("s_waitcnt vmcnt(12)" ::: "memory");
  SB0();
  __builtin_amdgcn_s_barrier();
  SB0();

  STEP_SCAN(sA1, r1a, r1b, r1c, r1d, 0);
  STEP_SCAN(sA2, r2a, r2b, r2c, r2d, 1);
  STEP_SCAN(sA3, r3a, r3b, r3c, r3d, 2);
}

// ---------------- K2: sequential scan over 32 chunk summaries (proven r10 code) ----------------
__device__ __forceinline__ void read_afragT64(const float* sAbuf, int row, int k0,
                                              short8& ah, short8& al) {
  const float* base = sAbuf + k0 * 64 + row;
  float d0 = base[0], d1 = base[64], d2 = base[128], d3 = base[192];
  float d4 = base[256], d5 = base[320], d6 = base[384], d7 = base[448];
  U8 h, l;
  u32 hu, lu;
  pk_split(d0, d1, hu, lu); h.u[0] = hu; l.u[0] = lu;
  pk_split(d2, d3, hu, lu); h.u[1] = hu; l.u[1] = lu;
  pk_split(d4, d5, hu, lu); h.u[2] = hu; l.u[2] = lu;
  pk_split(d6, d7, hu, lu); h.u[3] = hu; l.u[3] = lu;
  ah = h.s; al = l.s;
}

#define ISSUE_A16(PTRA, SBUF)                                                   \
  do {                                                                          \
    const float* gp_ = (PTRA);                                                  \
    float* sb_ = (SBUF);                                                        \
    _Pragma("unroll") for (int it_ = 0; it_ < 4; ++it_) {                       \
      const int off_ = (w * 4 + it_) * 256;                                     \
      __builtin_amdgcn_global_load_lds(                                         \
          (const __attribute__((address_space(1))) u32*)(gp_ + off_ + lane * 4),\
          (__attribute__((address_space(3))) u32*)(sb_ + off_),                 \
          16, 0, 0);                                                            \
    }                                                                           \
  } while (0)

#define SEQ_STEP(I, SCUR, SNXT)                                               \
  do {                                                                        \
    const int i_ = (I);                                                       \
    const bool more_ = (i_ + 1 < kNC);                                        \
    f32x4 nacc[4];                                                            \
    nacc[0] = b0; nacc[1] = b1; nacc[2] = b2; nacc[3] = b3;                   \
    if (more_) {                                                              \
      ISSUE_A16(srcA + (size_t)(e0 + i_ + 1) * kTile, SNXT);                  \
      LOAD_B4_INTO(b0, b1, b2, b3, srcB + (size_t)(e0 + i_ + 1) * kTile);     \
      SB0();                                                                  \
    }                                                                         \
    _Pragma("unroll") for (int ks = 0; ks < 2; ++ks) {                        \
      u32 p01h, p01l, p23h, p23l, q01h, q01l, q23h, q23l;                     \
      pk_split(acc[2 * ks][0], acc[2 * ks][1], p01h, p01l);                   \
      pk_split(acc[2 * ks][2], acc[2 * ks][3], p23h, p23l);                   \
      pk_split(acc[2 * ks + 1][0], acc[2 * ks + 1][1], q01h, q01l);           \
      pk_split(acc[2 * ks + 1][2], acc[2 * ks + 1][3], q23h, q23l);           \
      const short8 bfh = gather_frag(p01h, p23h, q01h, q23h, ad0, ad1, lowh); \
      const short8 bfl = gather_frag(p01l, p23l, q01l, q23l, ad0, ad1, lowh); \
      _Pragma("unroll") for (int cm = 0; cm < 4; ++cm) {                      \
        short8 ah, al;                                                        \
        read_afragT64(&(SCUR)[0], cm * 16 + l15, ks * 32 + q * 8, ah, al);    \
        nacc[cm] = mfma16(ah, bfh, nacc[cm]);                                 \
        nacc[cm] = mfma16(ah, bfl, nacc[cm]);                                 \
        nacc[cm] = mfma16(al, bfh, nacc[cm]);                                 \
      }                                                                       \
    }                                                                         \
    const int t_ = (i_ + 1) * kCH - 1;                                        \
    float* o_ = out + ((size_t)t_ * kBH + bh) * kTile;                        \
    _Pragma("unroll") for (int cm = 0; cm < 4; ++cm) {                        \
      *reinterpret_cast<f32x4*>(o_ + rowbase + cm * 16 + q * 4) = nacc[cm];   \
      acc[cm] = nacc[cm];                                                     \
    }                                                                         \
    if (more_) __syncthreads();                                               \
  } while (0)

__global__ __launch_bounds__(256, 4) void gdr_scan_seq(
    const float* __restrict__ srcA, const float* __restrict__ srcB,
    const float* __restrict__ S0, float* __restrict__ out) {
  __shared__ float sA0[4096], sA1b[4096];

  const int tid = threadIdx.x;
  const int lane = tid & 63, w = tid >> 6;
  const int q = lane >> 4, l15 = lane & 15;
  const int bh = blockIdx.x;
  const long e0 = (long)bh * kNC;
  const int rowbase = (w * 16 + l15) * 64;
  const int ad0 = (l15 + ((lane >> 4) & 1) * 32) * 4;
  const int ad1 = ad0 + 64;
  const bool lowh = lane < 32;

  f32x4 acc[4];
  {
    const float* Sb = S0 + (size_t)bh * kTile;
#pragma unroll
    for (int cm = 0; cm < 4; ++cm)
      acc[cm] = *reinterpret_cast<const f32x4*>(Sb + rowbase + cm * 16 + q * 4);
  }

  f32x4 b0, b1, b2, b3;
  ISSUE_A16(srcA + (size_t)e0 * kTile, sA0);
  LOAD_B4_INTO(b0, b1, b2, b3, srcB + (size_t)e0 * kTile);
  __syncthreads();

  int i = 0;
  while (true) {
    SEQ_STEP(i, sA0, sA1b);
    if (++i >= kNC) break;
    SEQ_STEP(i, sA1b, sA0);
    if (++i >= kNC) break;
  }
}

extern "C" void kernel_launch(void* const* d_in, const int* in_sizes, int n_in,
                              void* d_out, int out_size, void* d_ws, size_t ws_size,
                              hipStream_t stream) {
  const float* A  = (const float*)d_in[0];
  const float* Bm = (const float*)d_in[1];
  const float* S0 = (const float*)d_in[2];
  float* out = (float*)d_out;

  // workspace: PA[64*32], PB[64*32] tiles of 16 KB = 64 MB
  float* PA = (float*)d_ws;
  float* PB = PA + (size_t)kBH * kNC * kTile;

  // K1: chunk summaries over CH=4 elements. Block = (bh, ck); elem i at tile
  // (ck*4+i)*64 + bh. dst tile = blockIdx.
  gdr_fold4<<<dim3(kBH * kNC), dim3(256), 0, stream>>>(A, Bm, PA, PB);
  // K2: scan 32 summaries (tiles bh*32+i); writes chunk-end states t=4k+3.
  gdr_scan_seq<<<dim3(kBH), dim3(256), 0, stream>>>(PA, PB, S0, out);
  // K3: in-chunk recurrence, 3 steps; writes t = 4ck..4ck+2.
  gdr_scan4<<<dim3(kBH * kNC), dim3(256), 0, stream>>>(A, Bm, S0, out);
}

// Round 13
// 153.632 us; speedup vs baseline: 1.2870x; 1.2870x over previous
//
#include <hip/hip_runtime.h>

// Gated delta rule recurrence S_t = S_{t-1} @ A_t + B_t, outputs all S_t.
// T=128, B*H=64 chains, D=64. Two-level chunked scan, NC=16 chunks of CH=8.
//   K1 (fold): chunk summaries (PA,PB)           [1024 blocks x 7 steps]
//   K2 (scan): over 16 summaries -> chunk-end states into out [64 blocks]
//   K3 (scan): in-chunk recurrence -> remaining states        [1024 blocks]
// Split-bf16 MFMA (hi/lo, 3 products), transposed recurrence S^T <- A^T S^T.
// r13 KEY CHANGE: the C/D->B-operand gather moves OFF the LDS pipe.
// The pull pattern a(l) = (l&15) + 32*((l>>4)&1) is row-uniform per 16-lane
// row: [row0,row2,row0,row2] (and ^16 partner [1,3,1,3]) — built with
// v_permlane32_swap_b32 + v_permlane16_swap_b32 (pure VALU, gfx950):
//   d=s=v; p32swap -> d=[v0,v1,v0,v1], s=[v2,v3,v2,v3]
//          p16swap -> d=[v0,v2,v0,v2] (=v[a(l)]), s=[v1,v3,v1,v3] (=v[a^16])
// 64 ds_bpermute/step -> 0. A tiles: r12's verified pitch-65 LDS staging
// (width-4 DMA, per-row dest; <=2-way banks on column reads). Barriers:
// plain __syncthreads (r10 skeleton, known-correct).

constexpr int kT = 128;
constexpr int kBH = 64;
constexpr int kD = 64;
constexpr int kTile = kD * kD;
constexpr int kNC = 16;
constexpr int kCH = 8;
constexpr int kP = 65;  // LDS pitch (floats) for staged A tiles

typedef __attribute__((ext_vector_type(8))) short short8;
typedef __attribute__((ext_vector_type(4))) float f32x4;
using u32 = unsigned int;

union U8 { u32 u[4]; short8 s; };

__device__ __forceinline__ f32x4 mfma16(short8 a, short8 b, f32x4 c) {
  return __builtin_amdgcn_mfma_f32_16x16x32_bf16(a, b, c, 0, 0, 0);
}

// split 2 floats into packed hi/lo bf16 pairs (1 v_cvt_pk each + exact residual)
__device__ __forceinline__ void pk_split(float a, float b, u32& h, u32& l) {
  u32 hu;
  asm("v_cvt_pk_bf16_f32 %0, %1, %2" : "=v"(hu) : "v"(a), "v"(b));
  const float ra = a - __uint_as_float(hu << 16);
  const float rb = b - __uint_as_float(hu & 0xffff0000u);
  u32 lu;
  asm("v_cvt_pk_bf16_f32 %0, %1, %2" : "=v"(lu) : "v"(ra), "v"(rb));
  h = hu;
  l = lu;
}

// row-pattern shuffle: out_a[l] = v[a(l)], out_b[l] = v[a(l)^16], where
// a(l) = (l&15) + 32*((l>>4)&1). Pure VALU (permlane swaps), no LDS.
__device__ __forceinline__ void rowpat(u32 v, u32& oa, u32& ob) {
  u32 d = v, s = v;
  asm("v_permlane32_swap_b32 %0, %1" : "+v"(d), "+v"(s));  // d=[v0,v1,v0,v1] s=[v2,v3,v2,v3]
  asm("v_permlane16_swap_b32 %0, %1" : "+v"(d), "+v"(s));  // d=[v0,v2,v0,v2] s=[v1,v3,v1,v3]
  oa = d;
  ob = s;
}

// Build one K=32 B-operand fragment from two C/D tiles (X = tile 2ks, Y = 2ks+1),
// one plane. Replaces 8 ds_bpermute with 8 permlane swaps (VALU).
__device__ __forceinline__ short8 gather_frag_pl(u32 p01, u32 p23, u32 q01, u32 q23,
                                                 bool lowh) {
  u32 x0a, x0b, x1a, x1b, y0a, y0b, y1a, y1b;
  rowpat(p01, x0a, x0b);
  rowpat(p23, x1a, x1b);
  rowpat(q01, y0a, y0b);
  rowpat(q23, y1a, y1b);
  U8 r;
  r.u[0] = lowh ? x0a : y0a;
  r.u[1] = lowh ? x1a : y1a;
  r.u[2] = lowh ? x0b : y0b;
  r.u[3] = lowh ? x1b : y1b;
  return r.s;
}

// Read A^T fragment from pitch-65 row-major fp32 A tile in LDS:
// A[k0+j][row] at LDS dword (k0+j)*65 + row. Banks (k+row)%32 -> <=2-way.
__device__ __forceinline__ void read_afragT65(const float* sAbuf, int row, int k0,
                                              short8& ah, short8& al) {
  const float* base = sAbuf + k0 * kP + row;
  float d0 = base[0 * kP], d1 = base[1 * kP], d2 = base[2 * kP], d3 = base[3 * kP];
  float d4 = base[4 * kP], d5 = base[5 * kP], d6 = base[6 * kP], d7 = base[7 * kP];
  U8 h, l;
  u32 hu, lu;
  pk_split(d0, d1, hu, lu); h.u[0] = hu; l.u[0] = lu;
  pk_split(d2, d3, hu, lu); h.u[1] = hu; l.u[1] = lu;
  pk_split(d4, d5, hu, lu); h.u[2] = hu; l.u[2] = lu;
  pk_split(d6, d7, hu, lu); h.u[3] = hu; l.u[3] = lu;
  ah = h.s; al = l.s;
}

// Stage one A tile into pitch-65 LDS: 16 width-4 DMAs per wave, one row each
// (src = 256B contiguous per inst, coalesced; dest row base uniform).
#define ISSUE_A65(PTRA, SBUF)                                                   \
  do {                                                                          \
    const float* gp_ = (PTRA);                                                  \
    float* sb_ = (SBUF);                                                        \
    _Pragma("unroll") for (int it_ = 0; it_ < 16; ++it_) {                      \
      const int row_ = w * 16 + it_;                                            \
      __builtin_amdgcn_global_load_lds(                                         \
          (const __attribute__((address_space(1))) u32*)(gp_ + row_ * 64 + lane), \
          (__attribute__((address_space(3))) u32*)(sb_ + row_ * kP),            \
          4, 0, 0);                                                             \
    }                                                                           \
  } while (0)

#define LOAD_B4(PTRB)                                                          \
  do {                                                                         \
    const float* Bt_ = (PTRB);                                                 \
    b0 = *reinterpret_cast<const f32x4*>(Bt_ + rowbase + 0 * 16 + q * 4);      \
    b1 = *reinterpret_cast<const f32x4*>(Bt_ + rowbase + 1 * 16 + q * 4);      \
    b2 = *reinterpret_cast<const f32x4*>(Bt_ + rowbase + 2 * 16 + q * 4);      \
    b3 = *reinterpret_cast<const f32x4*>(Bt_ + rowbase + 3 * 16 + q * 4);      \
  } while (0)

// ---------------- fold: (pa,pb) <- fold of nElem (A,B) elements ----------------
// step J: issues element J+2 -> SNXT + B(J+2) at TOP, consumes b0..b3
// (B element J+1), computes with sA=SCUR (element J+1), drain barrier.
#define FOLD_STEP(J, SCUR, SNXT)                                              \
  do {                                                                        \
    const int j_ = (J);                                                       \
    const bool more_ = (j_ + 1 < nS);                                         \
    f32x4 npa[4], npb[4];                                                     \
    npb[0] = b0; npb[1] = b1; npb[2] = b2; npb[3] = b3;                       \
    _Pragma("unroll") for (int cm = 0; cm < 4; ++cm)                          \
        npa[cm] = (f32x4){0.f, 0.f, 0.f, 0.f};                                \
    if (more_) {                                                              \
      ISSUE_A65(srcA + (size_t)(e0 + (long)(j_ + 2) * elemStride) * kTile, SNXT); \
      LOAD_B4(srcB + (size_t)(e0 + (long)(j_ + 2) * elemStride) * kTile);     \
      __builtin_amdgcn_sched_barrier(0);                                      \
    }                                                                         \
    _Pragma("unroll") for (int ks = 0; ks < 2; ++ks) {                        \
      u32 pa01h, pa01l, pa23h, pa23l, qa01h, qa01l, qa23h, qa23l;             \
      u32 pb01h, pb01l, pb23h, pb23l, qb01h, qb01l, qb23h, qb23l;             \
      pk_split(apa[2 * ks][0], apa[2 * ks][1], pa01h, pa01l);                 \
      pk_split(apa[2 * ks][2], apa[2 * ks][3], pa23h, pa23l);                 \
      pk_split(apa[2 * ks + 1][0], apa[2 * ks + 1][1], qa01h, qa01l);         \
      pk_split(apa[2 * ks + 1][2], apa[2 * ks + 1][3], qa23h, qa23l);         \
      pk_split(apb[2 * ks][0], apb[2 * ks][1], pb01h, pb01l);                 \
      pk_split(apb[2 * ks][2], apb[2 * ks][3], pb23h, pb23l);                 \
      pk_split(apb[2 * ks + 1][0], apb[2 * ks + 1][1], qb01h, qb01l);         \
      pk_split(apb[2 * ks + 1][2], apb[2 * ks + 1][3], qb23h, qb23l);         \
      const short8 bah = gather_frag_pl(pa01h, pa23h, qa01h, qa23h, lowh);    \
      const short8 bal = gather_frag_pl(pa01l, pa23l, qa01l, qa23l, lowh);    \
      const short8 bbh = gather_frag_pl(pb01h, pb23h, qb01h, qb23h, lowh);    \
      const short8 bbl = gather_frag_pl(pb01l, pb23l, qb01l, qb23l, lowh);    \
      _Pragma("unroll") for (int cm = 0; cm < 4; ++cm) {                      \
        short8 ah, al;                                                        \
        read_afragT65(&(SCUR)[0], cm * 16 + l15, ks * 32 + q * 8, ah, al);    \
        npa[cm] = mfma16(ah, bah, npa[cm]);                                   \
        npa[cm] = mfma16(ah, bal, npa[cm]);                                   \
        npa[cm] = mfma16(al, bah, npa[cm]);                                   \
        npb[cm] = mfma16(ah, bbh, npb[cm]);                                   \
        npb[cm] = mfma16(ah, bbl, npb[cm]);                                   \
        npb[cm] = mfma16(al, bbh, npb[cm]);                                   \
      }                                                                       \
    }                                                                         \
    _Pragma("unroll") for (int cm = 0; cm < 4; ++cm) {                        \
      apa[cm] = npa[cm];                                                      \
      apb[cm] = npb[cm];                                                      \
    }                                                                         \
    if (more_) __syncthreads();                                               \
  } while (0)

__global__ __launch_bounds__(256, 4) void gdr_fold(
    const float* __restrict__ srcA, const float* __restrict__ srcB,
    float* __restrict__ dstA, float* __restrict__ dstB,
    int perChain, long chainBase, long idxBase, long elemStride, int nElem) {
  __shared__ float sA0[64 * kP], sA1[64 * kP];

  const int tid = threadIdx.x;
  const int lane = tid & 63, w = tid >> 6;
  const int q = lane >> 4, l15 = lane & 15;
  const int bh = blockIdx.x / perChain, id = blockIdx.x % perChain;
  const long e0 = (long)bh * chainBase + (long)id * idxBase;
  const int rowbase = (w * 16 + l15) * 64;
  const bool lowh = lane < 32;
  const int nS = nElem - 1;

  f32x4 apa[4], apb[4];
  {
    const float* At = srcA + (size_t)e0 * kTile;
    const float* Bt = srcB + (size_t)e0 * kTile;
#pragma unroll
    for (int cm = 0; cm < 4; ++cm) {
      apa[cm] = *reinterpret_cast<const f32x4*>(At + rowbase + cm * 16 + q * 4);
      apb[cm] = *reinterpret_cast<const f32x4*>(Bt + rowbase + cm * 16 + q * 4);
    }
  }

  f32x4 b0, b1, b2, b3;
  // prologue: stage element 1 -> sA0; preload B element 1.
  ISSUE_A65(srcA + (size_t)(e0 + elemStride) * kTile, sA0);
  LOAD_B4(srcB + (size_t)(e0 + elemStride) * kTile);
  __syncthreads();

  int j = 0;
  while (true) {
    FOLD_STEP(j, sA0, sA1);
    if (++j >= nS) break;
    FOLD_STEP(j, sA1, sA0);
    if (++j >= nS) break;
  }

  float* pao = dstA + (size_t)blockIdx.x * kTile;
  float* pbo = dstB + (size_t)blockIdx.x * kTile;
#pragma unroll
  for (int cm = 0; cm < 4; ++cm) {
    *reinterpret_cast<f32x4*>(pao + rowbase + cm * 16 + q * 4) = apa[cm];
    *reinterpret_cast<f32x4*>(pbo + rowbase + cm * 16 + q * 4) = apb[cm];
  }
}

// ---------------- scan: apply nSteps elements, write states into out ----------------
// step I: issues element I+1 -> SNXT + B(I+1) at TOP, consumes b0..b3
// (B element I), computes with sA=SCUR (element I), writes state, barrier.
#define SCAN_STEP(I, SCUR, SNXT)                                              \
  do {                                                                        \
    const int i_ = (I);                                                       \
    const bool more_ = (i_ + 1 < nSteps);                                     \
    f32x4 nacc[4];                                                            \
    nacc[0] = b0; nacc[1] = b1; nacc[2] = b2; nacc[3] = b3;                   \
    if (more_) {                                                              \
      ISSUE_A65(srcA + (size_t)(e0 + (long)(i_ + 1) * elemStride) * kTile, SNXT); \
      LOAD_B4(srcB + (size_t)(e0 + (long)(i_ + 1) * elemStride) * kTile);     \
      __builtin_amdgcn_sched_barrier(0);                                      \
    }                                                                         \
    _Pragma("unroll") for (int ks = 0; ks < 2; ++ks) {                        \
      u32 p01h, p01l, p23h, p23l, q01h, q01l, q23h, q23l;                     \
      pk_split(acc[2 * ks][0], acc[2 * ks][1], p01h, p01l);                   \
      pk_split(acc[2 * ks][2], acc[2 * ks][3], p23h, p23l);                   \
      pk_split(acc[2 * ks + 1][0], acc[2 * ks + 1][1], q01h, q01l);           \
      pk_split(acc[2 * ks + 1][2], acc[2 * ks + 1][3], q23h, q23l);           \
      const short8 bfh = gather_frag_pl(p01h, p23h, q01h, q23h, lowh);        \
      const short8 bfl = gather_frag_pl(p01l, p23l, q01l, q23l, lowh);        \
      _Pragma("unroll") for (int cm = 0; cm < 4; ++cm) {                      \
        short8 ah, al;                                                        \
        read_afragT65(&(SCUR)[0], cm * 16 + l15, ks * 32 + q * 8, ah, al);    \
        nacc[cm] = mfma16(ah, bfh, nacc[cm]);                                 \
        nacc[cm] = mfma16(ah, bfl, nacc[cm]);                                 \
        nacc[cm] = mfma16(al, bfh, nacc[cm]);                                 \
      }                                                                       \
    }                                                                         \
    const int t_ = tBase + (i_ + 1) * tStep - 1;                              \
    float* o_ = out + ((size_t)t_ * kBH + bh) * kTile;                        \
    _Pragma("unroll") for (int cm = 0; cm < 4; ++cm) {                        \
      *reinterpret_cast<f32x4*>(o_ + rowbase + cm * 16 + q * 4) = nacc[cm];   \
      acc[cm] = nacc[cm];                                                     \
    }                                                                         \
    if (more_) __syncthreads();                                               \
  } while (0)

__global__ __launch_bounds__(256, 4) void gdr_scan(
    const float* __restrict__ srcA, const float* __restrict__ srcB,
    const float* __restrict__ S0, float* __restrict__ out,
    int perChain, long chainBase, long idxBase, long elemStride,
    int nSteps, int tbMul, int tStep) {
  __shared__ float sA0[64 * kP], sA1[64 * kP];

  const int tid = threadIdx.x;
  const int lane = tid & 63, w = tid >> 6;
  const int q = lane >> 4, l15 = lane & 15;
  const int bh = blockIdx.x / perChain, id = blockIdx.x % perChain;
  const long e0 = (long)bh * chainBase + (long)id * idxBase;
  const int tBase = id * tbMul;
  const int rowbase = (w * 16 + l15) * 64;
  const bool lowh = lane < 32;

  f32x4 acc[4];
  {
    const float* Sb = (tBase == 0) ? (S0 + (size_t)bh * kTile)
                                   : (out + ((size_t)(tBase - 1) * kBH + bh) * kTile);
#pragma unroll
    for (int cm = 0; cm < 4; ++cm)
      acc[cm] = *reinterpret_cast<const f32x4*>(Sb + rowbase + cm * 16 + q * 4);
  }

  f32x4 b0, b1, b2, b3;
  // prologue: stage element 0 -> sA0; preload B element 0.
  ISSUE_A65(srcA + (size_t)e0 * kTile, sA0);
  LOAD_B4(srcB + (size_t)e0 * kTile);
  __syncthreads();

  int i = 0;
  while (true) {
    SCAN_STEP(i, sA0, sA1);
    if (++i >= nSteps) break;
    SCAN_STEP(i, sA1, sA0);
    if (++i >= nSteps) break;
  }
}

extern "C" void kernel_launch(void* const* d_in, const int* in_sizes, int n_in,
                              void* d_out, int out_size, void* d_ws, size_t ws_size,
                              hipStream_t stream) {
  const float* A  = (const float*)d_in[0];
  const float* Bm = (const float*)d_in[1];
  const float* S0 = (const float*)d_in[2];
  float* out = (float*)d_out;

  // workspace: PA[64*16], PB[64*16] tiles of 16 KB = 32 MB
  float* PA = (float*)d_ws;
  float* PB = PA + (size_t)kBH * kNC * kTile;

  // K1: chunk summaries. elements (ck*8+i)*64+bh, i=0..7
  gdr_fold<<<dim3(kBH * kNC), dim3(256), 0, stream>>>(
      A, Bm, PA, PB, kNC, 1L, (long)kCH * kBH, (long)kBH, kCH);
  // K2: scan 16 summaries (tiles bh*16+i); writes t = (i+1)*8-1 (7,15,...,127)
  gdr_scan<<<dim3(kBH), dim3(256), 0, stream>>>(
      PA, PB, S0, out, 1, (long)kNC, 0L, 1L, kNC, 0, kCH);
  // K3: in-chunk recurrence; elements (ck*8+i)*64+bh, start out[ck*8-1]/S0,
  //     writes t = ck*8+i for i=0..6
  gdr_scan<<<dim3(kBH * kNC), dim3(256), 0, stream>>>(
      A, Bm, S0, out, kNC, 1L, (long)kCH * kBH, (long)kBH, kCH - 1, kCH, 1);
}